// Round 9
// baseline (5671.440 us; speedup 1.0000x reference)
//
#include <hip/hip_runtime.h>

// LSTMForecast: B=256, T=512, IN=32, H=256, OUT=1, fp32.
// Round 9: cached ring reads via write-once epochs (depth-16 ring + per-epoch
//          acquire fence), wave-split L1 staging, dual MFMA accumulators.
//   - 256 blocks: (layer, sl16 j-slice, bg8). Weights bf16 hi+lo resident (AGPR).
//   - Producers: uncached ring stores (sc0 sc1 -> L3 fresh) + per-wave seq flags.
//   - Consumers: PLAIN CACHED uint4 ring loads. Safe because each ring address is
//     written once per epoch and every wave drops its L1/L2 copies at epoch start
//     (fence acquire agent = buffer_inv, 1/16 steps). 15/16 of reads now hit L2.
//   - 3-product split MFMA (hh+hl+lh), fp32-grade accuracy (R8 absmax 2.4e-7).

#define TT 512
#define RD 16        // ring depth (slots) == epoch length

typedef short v8s __attribute__((ext_vector_type(8)));
typedef float v4f __attribute__((ext_vector_type(4)));
typedef unsigned short u4h __attribute__((ext_vector_type(4)));

// ws byte offsets
constexpr size_t OFF_W0    = 0;          // [sl16][g4][kc9][spl2][lane64][e8] sh = 1,179,648 B
constexpr size_t OFF_W1    = 1179648;    // [sl16][g4][kc16][spl2][lane64][e8] = 2,097,152 B
constexpr size_t OFF_BC0   = 3276800;    // fp32[1024]
constexpr size_t OFF_BC1   = 3280896;    // fp32[1024]
constexpr size_t OFF_SEQ   = 3284992;    // int [layer2][bg8][producer16][wave4] = 4096 B
constexpr size_t OFF_RING0 = 3289088;    // RD slots x 8 bg x 32768 B = 4 MB
constexpr size_t OFF_RING1 = OFF_RING0 + (size_t)RD*8*32768;   // + 4 MB; end ~11.68 MB

__device__ __forceinline__ float bf2f(unsigned short h){ return __uint_as_float(((unsigned)h)<<16); }
__device__ __forceinline__ unsigned short f2bf(float f){
  unsigned u = __float_as_uint(f);
  u += 0x7FFF + ((u>>16)&1);
  return (unsigned short)(u>>16);
}
__device__ __forceinline__ float sigm(float v){ return 1.0f/(1.0f + expf(-v)); }
__device__ __forceinline__ float tanh_(float v){
  float a = fabsf(v);
  float e = expf(-2.0f*a);
  float r = (1.0f - e)/(1.0f + e);
  return copysignf(r, v);
}
__device__ __forceinline__ int ld_flag(const int* p){
  return __hip_atomic_load(p, __ATOMIC_RELAXED, __HIP_MEMORY_SCOPE_AGENT);
}
__device__ __forceinline__ void st_flag(int* p, int v){
  __hip_atomic_store(p, v, __ATOMIC_RELAXED, __HIP_MEMORY_SCOPE_AGENT);
}
__device__ __forceinline__ void st_r64(unsigned long long* p, unsigned long long v){
  __hip_atomic_store(p, v, __ATOMIC_RELAXED, __HIP_MEMORY_SCOPE_AGENT);
}

// poll NW contiguous seq words; returns wave-uniform min (>= need)
template<int NW>
__device__ __forceinline__ int poll_w(const int* base, int lane, int need, int kn){
  if (kn >= need) return kn;
  for(;;){
    int v = ld_flag(base + (lane & (NW-1)));
    v = min(v, __shfl_xor(v, 1, 64));
    v = min(v, __shfl_xor(v, 2, 64));
    v = min(v, __shfl_xor(v, 4, 64));
    v = min(v, __shfl_xor(v, 8, 64));
    if (NW > 16) v = min(v, __shfl_xor(v, 16, 64));
    if (NW > 32) v = min(v, __shfl_xor(v, 32, 64));
    if (v >= need) return v;
    __builtin_amdgcn_s_sleep(1);
  }
}

// stage NP producers' slices for this wave: cached uint4 loads -> LDS frag panel
template<int SSTR, int HSTR, int NP>
__device__ __forceinline__ void stage_c(const char* __restrict__ ringb, size_t slotbyte,
                                        int pbase, int lane, short* Afr, int cadd){
  const int seg = lane >> 5;            // sh = i*2 + seg
  const int l2  = lane & 31;
  uint4 v[NP][2];
  #pragma unroll
  for (int q = 0; q < NP; ++q){
    int p = pbase + q;
    size_t pb = (size_t)((p>>1)*128 + (p&1)*64);
    #pragma unroll
    for (int i = 0; i < 2; ++i){
      int sh = i*2 + seg;
      size_t u64i = pb + (size_t)((sh>>1)*2048 + (sh&1)*1024 + l2*2);
      v[q][i] = *(const uint4*)(ringb + slotbyte + u64i*8);
    }
  }
  #pragma unroll
  for (int q = 0; q < NP; ++q){
    int p = pbase + q;
    #pragma unroll
    for (int i = 0; i < 2; ++i){
      int sh = i*2 + seg;
      *(uint4*)(Afr + (sh>>1)*SSTR + (sh&1)*HSTR
                + ((p>>1)+cadd)*512 + ((p&1)*64 + l2*2)*4) = v[q][i];
    }
  }
}

// ---------------- pack kernel ----------------
__global__ void pack_all(const float* __restrict__ Wih0, const float* __restrict__ Whh0,
                         const float* __restrict__ bih0, const float* __restrict__ bhh0,
                         const float* __restrict__ Wih1, const float* __restrict__ Whh1,
                         const float* __restrict__ bih1, const float* __restrict__ bhh1,
                         char* __restrict__ ws, float* __restrict__ out){
  int idx = blockIdx.x*256 + threadIdx.x;
  if (idx < 589824){    // W0: [sl][g][kc9][spl][lane][e]
    int e = idx&7, lane = (idx>>3)&63, spl = (idx>>9)&1, r = idx>>10;
    int kc = r%9, r2 = r/9;
    int g = r2&3, sl = r2>>2;
    int row = g*256 + sl*16 + (lane&15);
    int k = kc*32 + (lane>>4)*8 + e;
    float w = (k < 32) ? Wih0[row*32 + k] : Whh0[row*256 + (k-32)];
    unsigned short hi = f2bf(w);
    ((unsigned short*)(ws + OFF_W0))[idx] = spl ? f2bf(w - bf2f(hi)) : hi;
    return;
  }
  idx -= 589824;
  if (idx < 1048576){   // W1: [sl][g][kc16][spl][lane][e]
    int e = idx&7, lane = (idx>>3)&63, spl = (idx>>9)&1, r = idx>>10;
    int kc = r&15, r2 = r>>4;
    int g = r2&3, sl = r2>>2;
    int row = g*256 + sl*16 + (lane&15);
    int k = kc*32 + (lane>>4)*8 + e;
    float w = (k < 256) ? Wih1[row*256 + k] : Whh1[row*256 + (k-256)];
    unsigned short hi = f2bf(w);
    ((unsigned short*)(ws + OFF_W1))[idx] = spl ? f2bf(w - bf2f(hi)) : hi;
    return;
  }
  idx -= 1048576;
  if (idx < 2048){      // combined biases [g*256+j]
    float* bc = (float*)(ws + (idx < 1024 ? OFF_BC0 : OFF_BC1));
    int j = idx & 1023;
    bc[j] = (idx < 1024) ? (bih0[j]+bhh0[j]) : (bih1[j]+bhh1[j]);
    return;
  }
  idx -= 2048;
  if (idx < 131072){    // zero ring slot RD-1 (h[-1]) of both rings
    int* rz = (int*)(ws + (idx < 65536 ? OFF_RING0 : OFF_RING1) + (size_t)(RD-1)*262144);
    rz[idx & 65535] = 0;
    return;
  }
  idx -= 131072;
  if (idx < 256){ out[idx] = 0.f; return; }
  idx -= 256;
  if (idx < 1024){ ((int*)(ws + OFF_SEQ))[idx] = 0; return; }
}

// ---------------- persistent layer worker ----------------
template<int LAYER>
__device__ void run_layer(const float* __restrict__ x, char* __restrict__ ws,
                          const float* __restrict__ Wfc, const float* __restrict__ bfc,
                          float* __restrict__ out, int bg, int sl,
                          short* Afr, float* gatesL, float* cst, unsigned short* hbuf){
  constexpr int NKC  = LAYER ? 16 : 9;       // K chunks per split half
  constexpr int HSTR = NKC*512;              // half stride (shorts)
  constexpr int SSTR = 2*HSTR;               // spl stride
  constexpr int NFR  = 2*NKC;                // B frags per wave

  int* seq0 = (int*)(ws + OFF_SEQ) + bg*64;
  int* seq1 = (int*)(ws + OFF_SEQ) + (8+bg)*64;
  const char* ring0b = (const char*)(ws + OFF_RING0);
  const char* ring1b = (const char*)(ws + OFF_RING1);
  unsigned long long* ring0w = (unsigned long long*)(ws + OFF_RING0);
  unsigned long long* ring1w = (unsigned long long*)(ws + OFF_RING1);

  const int tid  = threadIdx.x;
  const int lane = tid & 63;
  const int wv   = tid >> 6;       // wave == gate (i,f,g,o)
  const int m    = lane & 15;
  const int quad = lane >> 4;

  // ---- persistent B-fragments (land in unified VGPR/AGPR file) ----
  const unsigned short* wp = (const unsigned short*)(ws + (LAYER ? OFF_W1 : OFF_W0))
                             + (size_t)(sl*4 + wv)*NFR*512 + lane*8;
  v8s bfr[NFR];
  #pragma unroll
  for (int f = 0; f < NFR; ++f){
    v8s tmp = *(const v8s*)(wp + f*512);
    asm volatile("" : "+v"(tmp));            // anti-remat
    bfr[f] = tmp;
  }

  // ---- gate-phase constants: thread (bb, jp) owns (b=bb, j = sl*16 + jp*2 + p) ----
  const int bb = tid & 31, jp = tid >> 5;
  const float* bcp = (const float*)(ws + (LAYER ? OFF_BC1 : OFF_BC0));
  float bia[2][4];
  #pragma unroll
  for (int p = 0; p < 2; ++p)
    #pragma unroll
    for (int gg = 0; gg < 4; ++gg) bia[p][gg] = bcp[gg*256 + sl*16 + jp*2 + p];
  float wfcv[2] = {0.f, 0.f};
  if (LAYER == 1){ wfcv[0] = Wfc[sl*16 + jp*2]; wfcv[1] = Wfc[sl*16 + jp*2 + 1]; }
  float fcp = 0.f;

  const int half_b  = bb >> 4;
  const int laneloc = ((jp*2) >> 3)*16 + (bb & 15);
  const int e0h     = ((jp*2) & 7) >> 1;

  for (int i = tid; i < 544; i += 256) cst[i] = 0.f;
  __syncthreads();

  const int xb = tid >> 3, xs = tid & 7;     // x staging role (L0)
  int kn_a = 0, kn_b = 0, kn_bp = 0;         // cached flag minima (wave-uniform)

  for (int t = 0; t < TT; ++t){
    // ---- epoch boundary: drop L1/L2 copies of last pass's ring lines ----
    if ((t & (RD-1)) == 0) __builtin_amdgcn_fence(__ATOMIC_ACQUIRE, "agent");

    size_t slotb_prev = (size_t)((t+RD-1)&(RD-1))*262144 + (size_t)bg*32768;
    size_t slotb_cur  = (size_t)(t&(RD-1))*262144 + (size_t)bg*32768;
    size_t slotw_cur  = (size_t)(t&(RD-1))*32768 + (size_t)bg*4096;   // u64 units

    if (LAYER == 0){
      float4 xv = *(const float4*)(x + ((size_t)(bg*32 + xb)*TT + t)*32 + xs*4);
      // back-pressure: L1 must have consumed the ring0 slot we overwrite (depth RD)
      if (wv == 0 && t >= RD) kn_bp = poll_w<64>(seq1, lane, t-(RD-1), kn_bp);
      // wait my 4 producers' h0[t-1], stage (cached reads)
      kn_a = poll_w<16>(seq0 + 16*wv, lane, t, kn_a);
      asm volatile("" ::: "memory");
      stage_c<SSTR,HSTR,4>(ring0b, slotb_prev, wv*4, lane, Afr, 1);
      // x chunk (c=0) fragment writes
      {
        u4h hi4, lo4;
        hi4.x = f2bf(xv.x); lo4.x = f2bf(xv.x - bf2f(hi4.x));
        hi4.y = f2bf(xv.y); lo4.y = f2bf(xv.y - bf2f(hi4.y));
        hi4.z = f2bf(xv.z); lo4.z = f2bf(xv.z - bf2f(hi4.z));
        hi4.w = f2bf(xv.w); lo4.w = f2bf(xv.w - bf2f(hi4.w));
        int lx = (xs>>1)*16 + (xb&15), hx = xb>>4, ex = (xs&1)*4;
        *(u4h*)(Afr + 0*SSTR + hx*HSTR + lx*8 + ex) = hi4;
        *(u4h*)(Afr + 1*SSTR + hx*HSTR + lx*8 + ex) = lo4;
      }
    } else {
      // wave-split: waves 0-1 handle ring1 (h1[t-1]); waves 2-3 handle ring0 (h0[t])
      if (wv < 2){
        kn_b = poll_w<32>(seq1 + wv*32, lane, t, kn_b);
        asm volatile("" ::: "memory");
        stage_c<SSTR,HSTR,8>(ring1b, slotb_prev, wv*8, lane, Afr, 8);
      } else {
        kn_a = poll_w<32>(seq0 + (wv-2)*32, lane, t+1, kn_a);
        asm volatile("" ::: "memory");
        stage_c<SSTR,HSTR,8>(ring0b, slotb_cur, (wv-2)*8, lane, Afr, 0);
      }
    }
    __syncthreads();                           // B1: Afr complete

    // ---- MFMA: 3-product split, dual accumulators (halved dep chains) ----
    v4f a0a={0,0,0,0}, a0b={0,0,0,0}, a1a={0,0,0,0}, a1b={0,0,0,0};
    #pragma unroll
    for (int c = 0; c < NKC; ++c){
      v8s A0h = *(const v8s*)(Afr + 0*SSTR + 0*HSTR + c*512 + lane*8);
      v8s A1h = *(const v8s*)(Afr + 0*SSTR + 1*HSTR + c*512 + lane*8);
      v8s A0l = *(const v8s*)(Afr + 1*SSTR + 0*HSTR + c*512 + lane*8);
      v8s A1l = *(const v8s*)(Afr + 1*SSTR + 1*HSTR + c*512 + lane*8);
      v8s Bh = bfr[c*2+0], Bl = bfr[c*2+1];
      if (c & 1){
        a0b = __builtin_amdgcn_mfma_f32_16x16x32_bf16(A0h, Bh, a0b, 0,0,0);
        a0b = __builtin_amdgcn_mfma_f32_16x16x32_bf16(A0h, Bl, a0b, 0,0,0);
        a0b = __builtin_amdgcn_mfma_f32_16x16x32_bf16(A0l, Bh, a0b, 0,0,0);
        a1b = __builtin_amdgcn_mfma_f32_16x16x32_bf16(A1h, Bh, a1b, 0,0,0);
        a1b = __builtin_amdgcn_mfma_f32_16x16x32_bf16(A1h, Bl, a1b, 0,0,0);
        a1b = __builtin_amdgcn_mfma_f32_16x16x32_bf16(A1l, Bh, a1b, 0,0,0);
      } else {
        a0a = __builtin_amdgcn_mfma_f32_16x16x32_bf16(A0h, Bh, a0a, 0,0,0);
        a0a = __builtin_amdgcn_mfma_f32_16x16x32_bf16(A0h, Bl, a0a, 0,0,0);
        a0a = __builtin_amdgcn_mfma_f32_16x16x32_bf16(A0l, Bh, a0a, 0,0,0);
        a1a = __builtin_amdgcn_mfma_f32_16x16x32_bf16(A1h, Bh, a1a, 0,0,0);
        a1a = __builtin_amdgcn_mfma_f32_16x16x32_bf16(A1h, Bl, a1a, 0,0,0);
        a1a = __builtin_amdgcn_mfma_f32_16x16x32_bf16(A1l, Bh, a1a, 0,0,0);
      }
    }
    {
      v4f acc0 = a0a + a0b, acc1 = a1a + a1b;
      float* gw = gatesL + wv*544;
      #pragma unroll
      for (int r = 0; r < 4; ++r){
        gw[(quad*4 + r)*17 + m]      = acc0[r];
        gw[(16 + quad*4 + r)*17 + m] = acc1[r];
      }
    }
    __syncthreads();                           // B2: gates ready

    // ---- gate nonlinearity + state + hbuf ----
    {
      float hv[2];
      #pragma unroll
      for (int p = 0; p < 2; ++p){
        int jl = jp*2 + p;
        float gi = gatesL[0*544 + bb*17 + jl] + bia[p][0];
        float gf = gatesL[1*544 + bb*17 + jl] + bia[p][1];
        float gG = gatesL[2*544 + bb*17 + jl] + bia[p][2];
        float go = gatesL[3*544 + bb*17 + jl] + bia[p][3];
        float iv = sigm(gi), fv = sigm(gf), gv = tanh_(gG), ov = sigm(go);
        float cc = fv*cst[bb*17 + jl] + iv*gv;
        cst[bb*17 + jl] = cc;
        hv[p] = ov*tanh_(cc);
      }
      unsigned short h0h = f2bf(hv[0]), h1h = f2bf(hv[1]);
      unsigned short h0l = f2bf(hv[0] - bf2f(h0h)), h1l = f2bf(hv[1] - bf2f(h1h));
      unsigned* hb = (unsigned*)hbuf;
      hb[      half_b*128 + laneloc*4 + e0h] = (unsigned)h0h | ((unsigned)h1h << 16);
      hb[256 + half_b*128 + laneloc*4 + e0h] = (unsigned)h0l | ((unsigned)h1l << 16);
      if (LAYER == 1 && t == TT-1) fcp = hv[0]*wfcv[0] + hv[1]*wfcv[1];
    }
    __syncthreads();                           // B3: hbuf ready

    // ---- ring write (uncached, 1x 8B/thread) + per-wave release ----
    {
      unsigned long long v = ((const unsigned long long*)hbuf)[tid];
      size_t dst = slotw_cur + (size_t)(tid>>7)*2048 + (size_t)((tid>>6)&1)*1024
                 + (size_t)(sl>>1)*128 + (size_t)(sl&1)*64 + (tid&63);
      st_r64((LAYER ? ring1w : ring0w) + dst, v);
    }
    asm volatile("s_waitcnt vmcnt(0)" ::: "memory");
    if (lane == 0) st_flag((LAYER ? seq1 : seq0) + sl*4 + wv, t+1);
  }

  // ---- FC epilogue ----
  if (LAYER == 1){
    __syncthreads();
    gatesL[tid] = fcp;
    __syncthreads();
    if (tid < 32){
      float sm = 0.f;
      #pragma unroll
      for (int q = 0; q < 8; ++q) sm += gatesL[q*32 + tid];
      if (sl == 0) sm += bfc[0];
      atomicAdd(&out[bg*32 + tid], sm);
    }
  }
}

__global__ __launch_bounds__(256,1) void lstm_pipe(const float* __restrict__ x, char* __restrict__ ws,
                                                   const float* __restrict__ Wfc, const float* __restrict__ bfc,
                                                   float* __restrict__ out){
  __shared__ __align__(16) short Afr[32768];          // 65,536 B
  __shared__ __align__(16) float gatesL[2176];        //  8,704 B
  __shared__ __align__(16) float cst[544];            //  2,176 B
  __shared__ __align__(16) unsigned short hbuf[1024]; //  2,048 B
  const int bid = blockIdx.x;
  const int bg = bid & 7, r = bid >> 3, layer = r >> 4, sl = r & 15;
  if (layer == 0) run_layer<0>(x, ws, Wfc, bfc, out, bg, sl, Afr, gatesL, cst, hbuf);
  else            run_layer<1>(x, ws, Wfc, bfc, out, bg, sl, Afr, gatesL, cst, hbuf);
}

extern "C" void kernel_launch(void* const* d_in, const int* in_sizes, int n_in,
                              void* d_out, int out_size, void* d_ws, size_t ws_size,
                              hipStream_t stream) {
  const float* x    = (const float*)d_in[0];
  const float* Wih0 = (const float*)d_in[1];
  const float* Whh0 = (const float*)d_in[2];
  const float* bih0 = (const float*)d_in[3];
  const float* bhh0 = (const float*)d_in[4];
  const float* Wih1 = (const float*)d_in[5];
  const float* Whh1 = (const float*)d_in[6];
  const float* bih1 = (const float*)d_in[7];
  const float* bhh1 = (const float*)d_in[8];
  const float* Wfc  = (const float*)d_in[9];
  const float* bfc  = (const float*)d_in[10];
  float* out = (float*)d_out;
  char* ws   = (char*)d_ws;
  (void)in_sizes; (void)n_in; (void)out_size; (void)ws_size;

  // pack items: 589824+1048576+2048+131072+256+1024 = 1,772,800 = 6925*256
  pack_all<<<6925, 256, 0, stream>>>(Wih0, Whh0, bih0, bhh0, Wih1, Whh1, bih1, bhh1, ws, out);
  lstm_pipe<<<256, 256, 0, stream>>>(x, ws, Wfc, bfc, out);
}

// Round 10
// 3355.785 us; speedup vs baseline: 1.6900x; 1.6900x over previous
//
#include <hip/hip_runtime.h>

// LSTMForecast: B=256, T=512, IN=32, H=256, OUT=1, fp32.
// Round 10: R8 uncached protocol + 16B uncached ring transactions.
//   - 256 blocks: (layer, sl16 j-slice, bg8). Weights bf16 hi+lo resident (unified RF).
//   - NO fences, NO cached ring reads (R9's per-epoch fence = constant L2 purge, regressed).
//   - Ring loads/stores: global_*_dwordx4 sc0 sc1 inline asm (device-coherent, 16B)
//     -> half the L3 transactions of R8's 8B atomics. volatile-asm ordering:
//     loads ... s_waitcnt vmcnt(0) ... "+v" touch, then use.
//   - RD=16 slack; wave-split L1 staging; dual MFMA accumulators; 3-product split.

#define TT 512
#define RD 16        // ring depth (slots)

typedef short v8s __attribute__((ext_vector_type(8)));
typedef float v4f __attribute__((ext_vector_type(4)));
typedef unsigned v4u __attribute__((ext_vector_type(4)));
typedef unsigned short u4h __attribute__((ext_vector_type(4)));

// ws byte offsets
constexpr size_t OFF_W0    = 0;          // [sl16][g4][kc9][spl2][lane64][e8] sh = 1,179,648 B
constexpr size_t OFF_W1    = 1179648;    // [sl16][g4][kc16][spl2][lane64][e8] = 2,097,152 B
constexpr size_t OFF_BC0   = 3276800;    // fp32[1024]
constexpr size_t OFF_BC1   = 3280896;    // fp32[1024]
constexpr size_t OFF_SEQ   = 3284992;    // int [layer2][bg8][producer16][wave4] = 4096 B
constexpr size_t OFF_RING0 = 3289088;    // RD x 8 bg x 32768 B = 4 MB
constexpr size_t OFF_RING1 = OFF_RING0 + (size_t)RD*8*32768;   // + 4 MB; end ~11.68 MB

__device__ __forceinline__ float bf2f(unsigned short h){ return __uint_as_float(((unsigned)h)<<16); }
__device__ __forceinline__ unsigned short f2bf(float f){
  unsigned u = __float_as_uint(f);
  u += 0x7FFF + ((u>>16)&1);
  return (unsigned short)(u>>16);
}
__device__ __forceinline__ float sigm(float v){ return 1.0f/(1.0f + expf(-v)); }
__device__ __forceinline__ float tanh_(float v){
  float a = fabsf(v);
  float e = expf(-2.0f*a);
  float r = (1.0f - e)/(1.0f + e);
  return copysignf(r, v);
}
__device__ __forceinline__ int ld_flag(const int* p){
  return __hip_atomic_load(p, __ATOMIC_RELAXED, __HIP_MEMORY_SCOPE_AGENT);
}
__device__ __forceinline__ void st_flag(int* p, int v){
  __hip_atomic_store(p, v, __ATOMIC_RELAXED, __HIP_MEMORY_SCOPE_AGENT);
}
// 16B device-coherent (L1/L2-bypass) load/store, inline asm.
// volatile asm statements are mutually ordered; results only used after the
// s_waitcnt + "+v" touch barrier in the staging routine below.
__device__ __forceinline__ v4u ld_uc(const void* p){
  v4u r;
  asm volatile("global_load_dwordx4 %0, %1, off sc0 sc1" : "=v"(r) : "v"(p));
  return r;
}
__device__ __forceinline__ void st_uc(void* p, v4u v){
  asm volatile("global_store_dwordx4 %0, %1, off sc0 sc1" :: "v"(p), "v"(v) : "memory");
}

// poll NW contiguous seq words; returns wave-uniform min (>= need)
template<int NW>
__device__ __forceinline__ int poll_w(const int* base, int lane, int need, int kn){
  if (kn >= need) return kn;
  for(;;){
    int v = ld_flag(base + (lane & (NW-1)));
    v = min(v, __shfl_xor(v, 1, 64));
    v = min(v, __shfl_xor(v, 2, 64));
    v = min(v, __shfl_xor(v, 4, 64));
    v = min(v, __shfl_xor(v, 8, 64));
    if (NW > 16) v = min(v, __shfl_xor(v, 16, 64));
    if (NW > 32) v = min(v, __shfl_xor(v, 32, 64));
    if (v >= need) return v;
    __builtin_amdgcn_s_sleep(1);
  }
}

// stage NP producers' slices for this wave: 16B uncached loads -> LDS frag panel
template<int SSTR, int HSTR, int NP>
__device__ __forceinline__ void stage_uc(const char* __restrict__ ringb, size_t slotbyte,
                                         int pbase, int lane, short* Afr, int cadd){
  const int seg = lane >> 5;            // sh = i*2 + seg
  const int l2  = lane & 31;
  v4u v[NP][2];
  #pragma unroll
  for (int q = 0; q < NP; ++q){
    int p = pbase + q;
    size_t pb = (size_t)((p>>1)*128 + (p&1)*64);
    #pragma unroll
    for (int i = 0; i < 2; ++i){
      int sh = i*2 + seg;
      size_t u64i = pb + (size_t)((sh>>1)*2048 + (sh&1)*1024 + l2*2);
      v[q][i] = ld_uc(ringb + slotbyte + u64i*8);
    }
  }
  asm volatile("s_waitcnt vmcnt(0)" ::: "memory");
  #pragma unroll
  for (int q = 0; q < NP; ++q){
    #pragma unroll
    for (int i = 0; i < 2; ++i) asm volatile("" : "+v"(v[q][i]));
  }
  #pragma unroll
  for (int q = 0; q < NP; ++q){
    int p = pbase + q;
    #pragma unroll
    for (int i = 0; i < 2; ++i){
      int sh = i*2 + seg;
      *(v4u*)(Afr + (sh>>1)*SSTR + (sh&1)*HSTR
              + ((p>>1)+cadd)*512 + ((p&1)*64 + l2*2)*4) = v[q][i];
    }
  }
}

// ---------------- pack kernel ----------------
__global__ void pack_all(const float* __restrict__ Wih0, const float* __restrict__ Whh0,
                         const float* __restrict__ bih0, const float* __restrict__ bhh0,
                         const float* __restrict__ Wih1, const float* __restrict__ Whh1,
                         const float* __restrict__ bih1, const float* __restrict__ bhh1,
                         char* __restrict__ ws, float* __restrict__ out){
  int idx = blockIdx.x*256 + threadIdx.x;
  if (idx < 589824){    // W0: [sl][g][kc9][spl][lane][e]
    int e = idx&7, lane = (idx>>3)&63, spl = (idx>>9)&1, r = idx>>10;
    int kc = r%9, r2 = r/9;
    int g = r2&3, sl = r2>>2;
    int row = g*256 + sl*16 + (lane&15);
    int k = kc*32 + (lane>>4)*8 + e;
    float w = (k < 32) ? Wih0[row*32 + k] : Whh0[row*256 + (k-32)];
    unsigned short hi = f2bf(w);
    ((unsigned short*)(ws + OFF_W0))[idx] = spl ? f2bf(w - bf2f(hi)) : hi;
    return;
  }
  idx -= 589824;
  if (idx < 1048576){   // W1: [sl][g][kc16][spl][lane][e]
    int e = idx&7, lane = (idx>>3)&63, spl = (idx>>9)&1, r = idx>>10;
    int kc = r&15, r2 = r>>4;
    int g = r2&3, sl = r2>>2;
    int row = g*256 + sl*16 + (lane&15);
    int k = kc*32 + (lane>>4)*8 + e;
    float w = (k < 256) ? Wih1[row*256 + k] : Whh1[row*256 + (k-256)];
    unsigned short hi = f2bf(w);
    ((unsigned short*)(ws + OFF_W1))[idx] = spl ? f2bf(w - bf2f(hi)) : hi;
    return;
  }
  idx -= 1048576;
  if (idx < 2048){      // combined biases [g*256+j]
    float* bc = (float*)(ws + (idx < 1024 ? OFF_BC0 : OFF_BC1));
    int j = idx & 1023;
    bc[j] = (idx < 1024) ? (bih0[j]+bhh0[j]) : (bih1[j]+bhh1[j]);
    return;
  }
  idx -= 2048;
  if (idx < 131072){    // zero ring slot RD-1 (h[-1]) of both rings
    int* rz = (int*)(ws + (idx < 65536 ? OFF_RING0 : OFF_RING1) + (size_t)(RD-1)*262144);
    rz[idx & 65535] = 0;
    return;
  }
  idx -= 131072;
  if (idx < 256){ out[idx] = 0.f; return; }
  idx -= 256;
  if (idx < 1024){ ((int*)(ws + OFF_SEQ))[idx] = 0; return; }
}

// ---------------- persistent layer worker ----------------
template<int LAYER>
__device__ void run_layer(const float* __restrict__ x, char* __restrict__ ws,
                          const float* __restrict__ Wfc, const float* __restrict__ bfc,
                          float* __restrict__ out, int bg, int sl,
                          short* Afr, float* gatesL, float* cst, unsigned short* hbuf){
  constexpr int NKC  = LAYER ? 16 : 9;       // K chunks per split half
  constexpr int HSTR = NKC*512;              // half stride (shorts)
  constexpr int SSTR = 2*HSTR;               // spl stride
  constexpr int NFR  = 2*NKC;                // B frags per wave

  int* seq0 = (int*)(ws + OFF_SEQ) + bg*64;
  int* seq1 = (int*)(ws + OFF_SEQ) + (8+bg)*64;
  const char* ring0b = (const char*)(ws + OFF_RING0);
  const char* ring1b = (const char*)(ws + OFF_RING1);
  char* ringwb = (char*)(ws + (LAYER ? OFF_RING1 : OFF_RING0));

  const int tid  = threadIdx.x;
  const int lane = tid & 63;
  const int wv   = tid >> 6;       // wave == gate (i,f,g,o)
  const int m    = lane & 15;
  const int quad = lane >> 4;

  // ---- persistent B-fragments (unified VGPR/AGPR file) ----
  const unsigned short* wp = (const unsigned short*)(ws + (LAYER ? OFF_W1 : OFF_W0))
                             + (size_t)(sl*4 + wv)*NFR*512 + lane*8;
  v8s bfr[NFR];
  #pragma unroll
  for (int f = 0; f < NFR; ++f){
    v8s tmp = *(const v8s*)(wp + f*512);
    asm volatile("" : "+v"(tmp));            // anti-remat
    bfr[f] = tmp;
  }

  // ---- gate-phase constants: thread (bb, jp) owns (b=bb, j = sl*16 + jp*2 + p) ----
  const int bb = tid & 31, jp = tid >> 5;
  const float* bcp = (const float*)(ws + (LAYER ? OFF_BC1 : OFF_BC0));
  float bia[2][4];
  #pragma unroll
  for (int p = 0; p < 2; ++p)
    #pragma unroll
    for (int gg = 0; gg < 4; ++gg) bia[p][gg] = bcp[gg*256 + sl*16 + jp*2 + p];
  float wfcv[2] = {0.f, 0.f};
  if (LAYER == 1){ wfcv[0] = Wfc[sl*16 + jp*2]; wfcv[1] = Wfc[sl*16 + jp*2 + 1]; }
  float fcp = 0.f;

  const int half_b  = bb >> 4;
  const int laneloc = ((jp*2) >> 3)*16 + (bb & 15);
  const int e0h     = ((jp*2) & 7) >> 1;

  for (int i = tid; i < 544; i += 256) cst[i] = 0.f;
  __syncthreads();

  const int xb = tid >> 3, xs = tid & 7;     // x staging role (L0)
  int kn_a = 0, kn_b = 0, kn_bp = 0;         // cached flag minima (wave-uniform)

  for (int t = 0; t < TT; ++t){
    size_t slotb_prev = (size_t)((t+RD-1)&(RD-1))*262144 + (size_t)bg*32768;
    size_t slotb_cur  = (size_t)(t&(RD-1))*262144 + (size_t)bg*32768;

    if (LAYER == 0){
      float4 xv = *(const float4*)(x + ((size_t)(bg*32 + xb)*TT + t)*32 + xs*4);
      // back-pressure: L1 must have consumed the ring0 slot we overwrite (depth RD)
      if (wv == 0 && t >= RD) kn_bp = poll_w<64>(seq1, lane, t-(RD-1), kn_bp);
      // wait my 4 producers' h0[t-1], stage (uncached 16B)
      kn_a = poll_w<16>(seq0 + 16*wv, lane, t, kn_a);
      stage_uc<SSTR,HSTR,4>(ring0b, slotb_prev, wv*4, lane, Afr, 1);
      // x chunk (c=0) fragment writes
      {
        u4h hi4, lo4;
        hi4.x = f2bf(xv.x); lo4.x = f2bf(xv.x - bf2f(hi4.x));
        hi4.y = f2bf(xv.y); lo4.y = f2bf(xv.y - bf2f(hi4.y));
        hi4.z = f2bf(xv.z); lo4.z = f2bf(xv.z - bf2f(hi4.z));
        hi4.w = f2bf(xv.w); lo4.w = f2bf(xv.w - bf2f(hi4.w));
        int lx = (xs>>1)*16 + (xb&15), hx = xb>>4, ex = (xs&1)*4;
        *(u4h*)(Afr + 0*SSTR + hx*HSTR + lx*8 + ex) = hi4;
        *(u4h*)(Afr + 1*SSTR + hx*HSTR + lx*8 + ex) = lo4;
      }
    } else {
      // wave-split: waves 0-1 handle ring1 (h1[t-1]); waves 2-3 handle ring0 (h0[t])
      if (wv < 2){
        kn_b = poll_w<32>(seq1 + wv*32, lane, t, kn_b);
        stage_uc<SSTR,HSTR,8>(ring1b, slotb_prev, wv*8, lane, Afr, 8);
      } else {
        kn_a = poll_w<32>(seq0 + (wv-2)*32, lane, t+1, kn_a);
        stage_uc<SSTR,HSTR,8>(ring0b, slotb_cur, (wv-2)*8, lane, Afr, 0);
      }
    }
    __syncthreads();                           // B1: Afr complete

    // ---- MFMA: 3-product split, dual accumulators ----
    v4f a0a={0,0,0,0}, a0b={0,0,0,0}, a1a={0,0,0,0}, a1b={0,0,0,0};
    #pragma unroll
    for (int c = 0; c < NKC; ++c){
      v8s A0h = *(const v8s*)(Afr + 0*SSTR + 0*HSTR + c*512 + lane*8);
      v8s A1h = *(const v8s*)(Afr + 0*SSTR + 1*HSTR + c*512 + lane*8);
      v8s A0l = *(const v8s*)(Afr + 1*SSTR + 0*HSTR + c*512 + lane*8);
      v8s A1l = *(const v8s*)(Afr + 1*SSTR + 1*HSTR + c*512 + lane*8);
      v8s Bh = bfr[c*2+0], Bl = bfr[c*2+1];
      if (c & 1){
        a0b = __builtin_amdgcn_mfma_f32_16x16x32_bf16(A0h, Bh, a0b, 0,0,0);
        a0b = __builtin_amdgcn_mfma_f32_16x16x32_bf16(A0h, Bl, a0b, 0,0,0);
        a0b = __builtin_amdgcn_mfma_f32_16x16x32_bf16(A0l, Bh, a0b, 0,0,0);
        a1b = __builtin_amdgcn_mfma_f32_16x16x32_bf16(A1h, Bh, a1b, 0,0,0);
        a1b = __builtin_amdgcn_mfma_f32_16x16x32_bf16(A1h, Bl, a1b, 0,0,0);
        a1b = __builtin_amdgcn_mfma_f32_16x16x32_bf16(A1l, Bh, a1b, 0,0,0);
      } else {
        a0a = __builtin_amdgcn_mfma_f32_16x16x32_bf16(A0h, Bh, a0a, 0,0,0);
        a0a = __builtin_amdgcn_mfma_f32_16x16x32_bf16(A0h, Bl, a0a, 0,0,0);
        a0a = __builtin_amdgcn_mfma_f32_16x16x32_bf16(A0l, Bh, a0a, 0,0,0);
        a1a = __builtin_amdgcn_mfma_f32_16x16x32_bf16(A1h, Bh, a1a, 0,0,0);
        a1a = __builtin_amdgcn_mfma_f32_16x16x32_bf16(A1h, Bl, a1a, 0,0,0);
        a1a = __builtin_amdgcn_mfma_f32_16x16x32_bf16(A1l, Bh, a1a, 0,0,0);
      }
    }
    {
      v4f acc0 = a0a + a0b, acc1 = a1a + a1b;
      float* gw = gatesL + wv*544;
      #pragma unroll
      for (int r = 0; r < 4; ++r){
        gw[(quad*4 + r)*17 + m]      = acc0[r];
        gw[(16 + quad*4 + r)*17 + m] = acc1[r];
      }
    }
    __syncthreads();                           // B2: gates ready

    // ---- gate nonlinearity + state + hbuf ----
    {
      float hv[2];
      #pragma unroll
      for (int p = 0; p < 2; ++p){
        int jl = jp*2 + p;
        float gi = gatesL[0*544 + bb*17 + jl] + bia[p][0];
        float gf = gatesL[1*544 + bb*17 + jl] + bia[p][1];
        float gG = gatesL[2*544 + bb*17 + jl] + bia[p][2];
        float go = gatesL[3*544 + bb*17 + jl] + bia[p][3];
        float iv = sigm(gi), fv = sigm(gf), gv = tanh_(gG), ov = sigm(go);
        float cc = fv*cst[bb*17 + jl] + iv*gv;
        cst[bb*17 + jl] = cc;
        hv[p] = ov*tanh_(cc);
      }
      unsigned short h0h = f2bf(hv[0]), h1h = f2bf(hv[1]);
      unsigned short h0l = f2bf(hv[0] - bf2f(h0h)), h1l = f2bf(hv[1] - bf2f(h1h));
      unsigned* hb = (unsigned*)hbuf;
      hb[      half_b*128 + laneloc*4 + e0h] = (unsigned)h0h | ((unsigned)h1h << 16);
      hb[256 + half_b*128 + laneloc*4 + e0h] = (unsigned)h0l | ((unsigned)h1l << 16);
      if (LAYER == 1 && t == TT-1) fcp = hv[0]*wfcv[0] + hv[1]*wfcv[1];
    }
    __syncthreads();                           // B3: hbuf ready

    // ---- ring write: one 16B uncached store per even thread ----
    if ((tid & 1) == 0){
      v4u v = *(const v4u*)((const unsigned long long*)hbuf + tid);
      size_t dst = (size_t)(t&(RD-1))*32768 + (size_t)bg*4096
                 + (size_t)(tid>>7)*2048 + (size_t)((tid>>6)&1)*1024
                 + (size_t)(sl>>1)*128 + (size_t)(sl&1)*64 + (tid&63);
      st_uc(ringwb + dst*8, v);
    }
    asm volatile("s_waitcnt vmcnt(0)" ::: "memory");
    if (lane == 0) st_flag((LAYER ? seq1 : seq0) + sl*4 + wv, t+1);
  }

  // ---- FC epilogue ----
  if (LAYER == 1){
    __syncthreads();
    gatesL[tid] = fcp;
    __syncthreads();
    if (tid < 32){
      float sm = 0.f;
      #pragma unroll
      for (int q = 0; q < 8; ++q) sm += gatesL[q*32 + tid];
      if (sl == 0) sm += bfc[0];
      atomicAdd(&out[bg*32 + tid], sm);
    }
  }
}

__global__ __launch_bounds__(256,1) void lstm_pipe(const float* __restrict__ x, char* __restrict__ ws,
                                                   const float* __restrict__ Wfc, const float* __restrict__ bfc,
                                                   float* __restrict__ out){
  __shared__ __align__(16) short Afr[32768];          // 65,536 B
  __shared__ __align__(16) float gatesL[2176];        //  8,704 B
  __shared__ __align__(16) float cst[544];            //  2,176 B
  __shared__ __align__(16) unsigned short hbuf[1024]; //  2,048 B
  const int bid = blockIdx.x;
  // bid&7 = bg -> all 32 blocks of a bg share one XCD under round-robin (perf only)
  const int bg = bid & 7, r = bid >> 3, layer = r >> 4, sl = r & 15;
  if (layer == 0) run_layer<0>(x, ws, Wfc, bfc, out, bg, sl, Afr, gatesL, cst, hbuf);
  else            run_layer<1>(x, ws, Wfc, bfc, out, bg, sl, Afr, gatesL, cst, hbuf);
}

extern "C" void kernel_launch(void* const* d_in, const int* in_sizes, int n_in,
                              void* d_out, int out_size, void* d_ws, size_t ws_size,
                              hipStream_t stream) {
  const float* x    = (const float*)d_in[0];
  const float* Wih0 = (const float*)d_in[1];
  const float* Whh0 = (const float*)d_in[2];
  const float* bih0 = (const float*)d_in[3];
  const float* bhh0 = (const float*)d_in[4];
  const float* Wih1 = (const float*)d_in[5];
  const float* Whh1 = (const float*)d_in[6];
  const float* bih1 = (const float*)d_in[7];
  const float* bhh1 = (const float*)d_in[8];
  const float* Wfc  = (const float*)d_in[9];
  const float* bfc  = (const float*)d_in[10];
  float* out = (float*)d_out;
  char* ws   = (char*)d_ws;
  (void)in_sizes; (void)n_in; (void)out_size; (void)ws_size;

  // pack items: 589824+1048576+2048+131072+256+1024 = 1,772,800 = 6925*256
  pack_all<<<6925, 256, 0, stream>>>(Wih0, Whh0, bih0, bhh0, Wih1, Whh1, bih1, bhh1, ws, out);
  lstm_pipe<<<256, 256, 0, stream>>>(x, ws, Wfc, bfc, out);
}